// Round 1
// baseline (365.886 us; speedup 1.0000x reference)
//
#include <hip/hip_runtime.h>
#include <math.h>

// Problem constants (from reference)
#define NSAMP 16
#define NPTS  512
#define MDIM  4096     // 64*64 grid
#define NIT   100
#define TPB   256
#define EPT   16       // MDIM / TPB elements per thread

// ws layout (floats)
#define OFF_BETA 0
#define OFF_WD   (NSAMP * MDIM)            // 65536: 8192 per-row wd partials
#define OFF_LOSS (OFF_WD + NSAMP * NPTS)   // 73728: 16 per-sample loss
#define OFF_OT   (OFF_LOSS + NSAMP)        // 73744: 16 per-sample ot_obj

// JAX RNG path: 1 = jax_threefry_partitionable (default True since jax 0.4.36)
// If validation fails with moderate absmax, flip to 0 (legacy path).
#define PARTITIONABLE 1

// ---------------- Threefry-2x32 (JAX-exact: 20 rounds, 5 key injections) ----
__device__ __forceinline__ void tf2x32(unsigned k0, unsigned k1,
                                       unsigned c0, unsigned c1,
                                       unsigned &o0, unsigned &o1)
{
  unsigned ks2 = k0 ^ k1 ^ 0x1BD11BDAu;
  unsigned x0 = c0 + k0, x1 = c1 + k1;
#define ROT(r) x0 += x1; x1 = (x1 << (r)) | (x1 >> (32 - (r))); x1 ^= x0;
#define G0 ROT(13) ROT(15) ROT(26) ROT(6)
#define G1 ROT(17) ROT(29) ROT(16) ROT(24)
  G0 x0 += k1;  x1 += ks2 + 1u;
  G1 x0 += ks2; x1 += k0  + 2u;
  G0 x0 += k0;  x1 += k1  + 3u;
  G1 x0 += k1;  x1 += ks2 + 4u;
  G0 x0 += ks2; x1 += k0  + 5u;
#undef G0
#undef G1
#undef ROT
  o0 = x0; o1 = x1;
}

// idx[f] for flat f in [0,1600): replicates
// jax.random.randint(key(1), (16,100), 0, 512).ravel()[f]
// (span=512 -> multiplier=0 -> only lower_bits = random_bits(split(key)[1]) matter)
__device__ __forceinline__ int rand_idx(int f)
{
#if PARTITIONABLE
  unsigned ka, kb, w0, w1;
  tf2x32(0u, 1u, 0u, 1u, ka, kb);            // split(key(1))[1] : ctr=(0,1)
  tf2x32(ka, kb, 0u, (unsigned)f, w0, w1);   // random_bits elem f : ctr=(0,f)
  return (int)((w0 ^ w1) & 511u);
#else
  unsigned a0, a1, b0, b1, w0, w1;
  tf2x32(0u, 1u, 0u, 2u, a0, a1);            // split original: counts [0,1]x[2,3]
  tf2x32(0u, 1u, 1u, 3u, b0, b1);            // k2 = (second words)
  if (f < 800) { tf2x32(a1, b1, (unsigned)f, (unsigned)(f + 800), w0, w1); return (int)(w0 & 511u); }
  else         { tf2x32(a1, b1, (unsigned)(f - 800), (unsigned)f, w0, w1); return (int)(w1 & 511u); }
#endif
}

// ---------------- block reductions (256 threads = 4 waves) ------------------
__device__ __forceinline__ float blockMax(float v, float *red)
{
  #pragma unroll
  for (int off = 32; off > 0; off >>= 1)
    v = fmaxf(v, __shfl_xor(v, off, 64));
  __syncthreads();
  if ((threadIdx.x & 63) == 0) red[threadIdx.x >> 6] = v;
  __syncthreads();
  return fmaxf(fmaxf(red[0], red[1]), fmaxf(red[2], red[3]));
}

__device__ __forceinline__ float blockSum(float v, float *red)
{
  #pragma unroll
  for (int off = 32; off > 0; off >>= 1)
    v += __shfl_xor(v, off, 64);
  __syncthreads();
  if ((threadIdx.x & 63) == 0) red[threadIdx.x >> 6] = v;
  __syncthreads();
  return (red[0] + red[1]) + (red[2] + red[3]);
}

// ---------------- Kernel A: per-sample ASGD scan ----------------------------
__global__ __launch_bounds__(TPB) void kern_scan(
    const float *__restrict__ normed, const float *__restrict__ unnormed,
    const float *__restrict__ pts, float *__restrict__ ws)
{
#pragma clang fp contract(off)
  const int s = blockIdx.x;
  const int t = threadIdx.x;
  __shared__ float red[4];
  __shared__ float px[NPTS], py[NPTS];
  __shared__ int   sidx[NIT];

  for (int i = t; i < NPTS; i += TPB) {
    px[i] = pts[(s * NPTS + i) * 2 + 0];
    py[i] = pts[(s * NPTS + i) * 2 + 1];
  }
  if (t < NIT) sidx[t] = rand_idx(s * NIT + t);
  __syncthreads();

  float b[EPT], lb[EPT], cur[EPT], ave[EPT], cx[EPT], cy[EPT];
  #pragma unroll
  for (int l = 0; l < EPT; ++l) {
    const int j = l * TPB + t;
    const float bv = normed[s * MDIM + j];
    b[l]  = bv;
    lb[l] = logf(bv);
    cur[l] = 0.f; ave[l] = 0.f;
    cx[l] = (float)((j & 63) * 8 + 4);   // COOD[j%64]
    cy[l] = (float)((j >> 6) * 8 + 4);   // COOD[j/64]
  }

  const float av = 1.0f / 512.0f;          // a_i
  const float lr = 1.0f / (av / 10.0f);    // 1/max(a/REG), exact replication

  for (int k = 1; k <= NIT; ++k) {
    const int   i = sidx[k - 1];
    const float x = px[i], y = py[i];
    const float xx = x * x, yy = y * y;
    const float m2x = -2.0f * x, m2y = -2.0f * y;

    float z[EPT];
    float mx = -INFINITY;
    #pragma unroll
    for (int l = 0; l < EPT; ++l) {
      // replicate ((-2x)*cood + x*x) + cood*cood, then y_dis + x_dis
      const float xd  = m2x * cx[l] + xx + cx[l] * cx[l];
      const float yd  = m2y * cy[l] + yy + cy[l] * cy[l];
      const float Mij = yd + xd;
      const float zz  = (cur[l] - Mij) / 10.0f + lb[l];
      z[l] = zz;
      mx = fmaxf(mx, zz);
    }
    mx = blockMax(mx, red);

    float psum = 0.f;
    #pragma unroll
    for (int l = 0; l < EPT; ++l) {
      const float e = expf(z[l] - mx);
      z[l] = e;
      psum += e;
    }
    const float ssum = blockSum(psum, red);

    const float kf   = (float)k;
    const float step = lr / sqrtf(kf);
    const float om   = 1.0f - 1.0f / kf;
    #pragma unroll
    for (int l = 0; l < EPT; ++l) {
      const float khi = z[l] / ssum;
      cur[l] = cur[l] + step * (b[l] - khi);
      ave[l] = cur[l] / kf + om * ave[l];
    }
  }

  // epilogue: beta out, per-sample ot_obj & loss
  float src[EPT];
  #pragma unroll
  for (int l = 0; l < EPT; ++l) {
    const int j = l * TPB + t;
    src[l] = unnormed[s * MDIM + j];
    ws[OFF_BETA + s * MDIM + j] = ave[l];
  }
  float p_sc = 0.f, p_s1 = 0.f, p_ot = 0.f;
  #pragma unroll
  for (int l = 0; l < EPT; ++l) {
    p_sc += src[l];
    p_s1 += src[l] * ave[l];
    p_ot += b[l] * ave[l];
  }
  const float sc = blockSum(p_sc, red);
  const float S1 = blockSum(p_s1, red);
  const float ot = blockSum(p_ot, red);
  const float denom = sc * sc + 1e-16f;
  const float c1 = sc / denom, c2 = S1 / denom;
  float pl = 0.f;
  #pragma unroll
  for (int l = 0; l < EPT; ++l)
    pl += src[l] * (c1 * ave[l] - c2);
  const float loss = blockSum(pl, red);
  if (t == 0) {
    ws[OFF_LOSS + s] = loss;
    ws[OFF_OT + s]   = ot;
  }
}

// ---------------- Kernel B: per-row logsumexp + wd partial ------------------
__global__ __launch_bounds__(TPB) void kern_rows(
    const float *__restrict__ normed, const float *__restrict__ pts,
    float *__restrict__ ws)
{
#pragma clang fp contract(off)
  const int gid = blockIdx.x;
  const int s = gid >> 9;
  const int i = gid & 511;
  const int t = threadIdx.x;
  __shared__ float red[4];

  const float x = pts[(s * NPTS + i) * 2 + 0];
  const float y = pts[(s * NPTS + i) * 2 + 1];
  const float xx = x * x, yy = y * y;
  const float m2x = -2.0f * x, m2y = -2.0f * y;

  float z[EPT], Mv[EPT];
  float mx = -INFINITY;
  #pragma unroll
  for (int l = 0; l < EPT; ++l) {
    const int j = l * TPB + t;
    const float cxv = (float)((j & 63) * 8 + 4);
    const float cyv = (float)((j >> 6) * 8 + 4);
    const float xd  = m2x * cxv + xx + cxv * cxv;
    const float yd  = m2y * cyv + yy + cyv * cyv;
    const float Mij = yd + xd;
    const float bv   = normed[s * MDIM + j];
    const float beta = ws[OFF_BETA + s * MDIM + j];
    const float zz = (beta - Mij) / 10.0f + logf(bv);
    Mv[l] = Mij;
    z[l]  = zz;
    mx = fmaxf(mx, zz);
  }
  mx = blockMax(mx, red);

  float pe = 0.f, pm = 0.f;
  #pragma unroll
  for (int l = 0; l < EPT; ++l) {
    const float e = expf(z[l] - mx);
    pe += e;
    pm += e * Mv[l];
  }
  const float se = blockSum(pe, red);
  const float sm = blockSum(pm, red);
  // wd_row = a_i * sum(e*M)/sum(e)  ==  sum_j dis*pi for this row
  if (t == 0)
    ws[OFF_WD + gid] = (1.0f / 512.0f) * (sm / se);
}

// ---------------- Kernel C: deterministic final reduce ----------------------
__global__ __launch_bounds__(TPB) void kern_final(const float *__restrict__ ws,
                                                  float *__restrict__ out)
{
  const int t = threadIdx.x;
  __shared__ float red[4];
  float v = 0.f;
  for (int i = t; i < NSAMP * NPTS; i += TPB) v += ws[OFF_WD + i];
  const float wd = blockSum(v, red);
  if (t == 0) {
    float ls = 0.f, ot = 0.f;
    for (int s = 0; s < NSAMP; ++s) { ls += ws[OFF_LOSS + s]; ot += ws[OFF_OT + s]; }
    out[0] = ls;   // loss.sum()
    out[1] = wd;   // wd.sum()
    out[2] = ot;   // ot_obj.sum()
  }
}

extern "C" void kernel_launch(void* const* d_in, const int* in_sizes, int n_in,
                              void* d_out, int out_size, void* d_ws, size_t ws_size,
                              hipStream_t stream)
{
  (void)in_sizes; (void)n_in; (void)out_size; (void)ws_size;
  const float *normed   = (const float *)d_in[0];
  const float *unnormed = (const float *)d_in[1];
  const float *pts      = (const float *)d_in[2];
  float *out = (float *)d_out;
  float *ws  = (float *)d_ws;

  kern_scan <<<dim3(NSAMP),        dim3(TPB), 0, stream>>>(normed, unnormed, pts, ws);
  kern_rows <<<dim3(NSAMP * NPTS), dim3(TPB), 0, stream>>>(normed, pts, ws);
  kern_final<<<dim3(1),            dim3(TPB), 0, stream>>>(ws, out);
}

// Round 2
// 164.866 us; speedup vs baseline: 2.2193x; 2.2193x over previous
//
#include <hip/hip_runtime.h>
#include <math.h>

// Problem constants (from reference)
#define NSAMP 16
#define NPTS  512
#define MDIM  4096     // 64*64 grid
#define NIT   100
#define TPB   256
#define EPT   16       // MDIM / TPB elements per thread

// ws layout (floats)
#define OFF_W    0                          // 16*4096: w[j] = 0.1*beta_j + ln(b_j)
#define OFF_WD   (NSAMP * MDIM)             // 8192 per-row wd partials
#define OFF_LOSS (OFF_WD + NSAMP * NPTS)    // 16 per-sample loss
#define OFF_OT   (OFF_LOSS + NSAMP)         // 16 per-sample ot_obj

// JAX RNG path: partitionable threefry (verified correct in R0: absmax 5.45e-6)
#define PARTITIONABLE 1

// ---------------- Threefry-2x32 (JAX-exact: 20 rounds, 5 key injections) ----
__device__ __forceinline__ void tf2x32(unsigned k0, unsigned k1,
                                       unsigned c0, unsigned c1,
                                       unsigned &o0, unsigned &o1)
{
  unsigned ks2 = k0 ^ k1 ^ 0x1BD11BDAu;
  unsigned x0 = c0 + k0, x1 = c1 + k1;
#define ROT(r) x0 += x1; x1 = (x1 << (r)) | (x1 >> (32 - (r))); x1 ^= x0;
#define G0 ROT(13) ROT(15) ROT(26) ROT(6)
#define G1 ROT(17) ROT(29) ROT(16) ROT(24)
  G0 x0 += k1;  x1 += ks2 + 1u;
  G1 x0 += ks2; x1 += k0  + 2u;
  G0 x0 += k0;  x1 += k1  + 3u;
  G1 x0 += k1;  x1 += ks2 + 4u;
  G0 x0 += ks2; x1 += k0  + 5u;
#undef G0
#undef G1
#undef ROT
  o0 = x0; o1 = x1;
}

__device__ __forceinline__ int rand_idx(int f)
{
#if PARTITIONABLE
  unsigned ka, kb, w0, w1;
  tf2x32(0u, 1u, 0u, 1u, ka, kb);            // split(key(1))[1]
  tf2x32(ka, kb, 0u, (unsigned)f, w0, w1);   // random_bits elem f
  return (int)((w0 ^ w1) & 511u);
#else
  unsigned a0, a1, b0, b1, w0, w1;
  tf2x32(0u, 1u, 0u, 2u, a0, a1);
  tf2x32(0u, 1u, 1u, 3u, b0, b1);
  if (f < 800) { tf2x32(a1, b1, (unsigned)f, (unsigned)(f + 800), w0, w1); return (int)(w0 & 511u); }
  else         { tf2x32(a1, b1, (unsigned)(f - 800), (unsigned)f, w0, w1); return (int)(w1 & 511u); }
#endif
}

// ---------------- wave64 reductions via DPP (full-rate VALU, no LDS) --------
// row_shr:1/2/4/8 then row_bcast:15, row_bcast:31 -> full reduce lands in lane 63.
// bound_ctrl=false + identity in `old` keeps invalid-source lanes neutral.
template<int CTRL>
__device__ __forceinline__ float dpp_mv(float v, float id)
{
  return __int_as_float(__builtin_amdgcn_update_dpp(
      __float_as_int(id), __float_as_int(v), CTRL, 0xF, 0xF, false));
}

__device__ __forceinline__ float waveMax(float v)
{
  v = fmaxf(v, dpp_mv<0x111>(v, -INFINITY));
  v = fmaxf(v, dpp_mv<0x112>(v, -INFINITY));
  v = fmaxf(v, dpp_mv<0x114>(v, -INFINITY));
  v = fmaxf(v, dpp_mv<0x118>(v, -INFINITY));
  v = fmaxf(v, dpp_mv<0x142>(v, -INFINITY));
  v = fmaxf(v, dpp_mv<0x143>(v, -INFINITY));
  return __int_as_float(__builtin_amdgcn_readlane(__float_as_int(v), 63));
}

__device__ __forceinline__ float waveSum(float v)
{
  v += dpp_mv<0x111>(v, 0.0f);
  v += dpp_mv<0x112>(v, 0.0f);
  v += dpp_mv<0x114>(v, 0.0f);
  v += dpp_mv<0x118>(v, 0.0f);
  v += dpp_mv<0x142>(v, 0.0f);
  v += dpp_mv<0x143>(v, 0.0f);
  return __int_as_float(__builtin_amdgcn_readlane(__float_as_int(v), 63));
}

__device__ __forceinline__ float blockSum(float v, float *red4)
{
  v = waveSum(v);
  __syncthreads();                       // WAR-protect red4 reuse
  if ((threadIdx.x & 63) == 0) red4[threadIdx.x >> 6] = v;
  __syncthreads();
  return (red4[0] + red4[1]) + (red4[2] + red4[3]);
}

// ---------------- Kernel A: per-sample ASGD scan ----------------------------
// State per element j (transformed units):
//   czh[j]   = 0.1*cur[j] + ln(b_j) - hx_j,  hx_j = 0.1*(cx^2+cy^2)
//   avezh[j] = same recurrence as ave (affine transform commutes; weights sum to 1)
// z_j = (cur-M)/10 + ln b = fma(0.2x, cx, fma(0.2y, cy, czh - 0.1*(x^2+y^2)))
// beta_j = (avezh + hx - ln b)*10
__global__ __launch_bounds__(TPB, 1) void kern_scan(
    const float *__restrict__ normed, const float *__restrict__ unnormed,
    const float *__restrict__ pts, float *__restrict__ ws)
{
  const int s = blockIdx.x;
  const int t = threadIdx.x;
  const int w = t >> 6;
  __shared__ float px[NPTS], py[NPTS];
  __shared__ int   sidx[NIT];
  __shared__ float xch[2][8];     // rotating per-wave (m, s) exchange
  __shared__ float red[4];        // epilogue block sums

  for (int i = t; i < NPTS; i += TPB) {
    px[i] = pts[(s * NPTS + i) * 2 + 0];
    py[i] = pts[(s * NPTS + i) * 2 + 1];
  }
  if (t < NIT) sidx[t] = rand_idx(s * NIT + t);

  float b[EPT], czh[EPT], avezh[EPT], cx[EPT], cy[EPT];
  #pragma unroll
  for (int l = 0; l < EPT; ++l) {
    const int j = l * TPB + t;
    const float bv = normed[s * MDIM + j];
    b[l] = bv;
    const float cxl = (float)((j & 63) * 8 + 4);
    const float cyl = (float)((j >> 6) * 8 + 4);
    cx[l] = cxl; cy[l] = cyl;
    const float hx = 0.1f * (cxl * cxl + cyl * cyl);
    czh[l]   = __logf(bv) - hx;     // cur=0
    avezh[l] = 0.f;
  }
  __syncthreads();

  const float av0 = 1.0f / 512.0f;
  const float lr  = 1.0f / (av0 / 10.0f);   // constant-folded, matches ref

  for (int k = 1; k <= NIT; ++k) {
    const int   i   = sidx[k - 1];
    const float x = px[i], y = py[i];
    const float p2x = 0.2f * x, p2y = 0.2f * y;
    const float sxy = 0.1f * (x * x + y * y);

    float z[EPT];
    #pragma unroll
    for (int l = 0; l < EPT; ++l)
      z[l] = fmaf(p2x, cx[l], fmaf(p2y, cy[l], czh[l] - sxy));

    // local max, 4-way tree for latency
    float m0 = z[0], m1 = z[1], m2 = z[2], m3 = z[3];
    #pragma unroll
    for (int l = 4; l < EPT; l += 4) {
      m0 = fmaxf(m0, z[l]); m1 = fmaxf(m1, z[l + 1]);
      m2 = fmaxf(m2, z[l + 2]); m3 = fmaxf(m3, z[l + 3]);
    }
    const float mw = waveMax(fmaxf(fmaxf(m0, m1), fmaxf(m2, m3)));

    float a0 = 0.f, a1 = 0.f, a2 = 0.f, a3 = 0.f;
    #pragma unroll
    for (int l = 0; l < EPT; l += 4) {
      float e0 = __expf(z[l] - mw);     z[l]     = e0; a0 += e0;
      float e1 = __expf(z[l + 1] - mw); z[l + 1] = e1; a1 += e1;
      float e2 = __expf(z[l + 2] - mw); z[l + 2] = e2; a2 += e2;
      float e3 = __expf(z[l + 3] - mw); z[l + 3] = e3; a3 += e3;
    }
    const float sw = waveSum((a0 + a1) + (a2 + a3));

    // single-barrier cross-wave online-softmax merge
    float *buf = xch[k & 1];
    if ((t & 63) == 0) { buf[2 * w] = mw; buf[2 * w + 1] = sw; }
    __syncthreads();
    const float M0 = buf[0], S0 = buf[1], M1 = buf[2], S1v = buf[3];
    const float M2 = buf[4], S2 = buf[5], M3 = buf[6], S3 = buf[7];
    const float ms = fmaxf(fmaxf(M0, M1), fmaxf(M2, M3));
    const float S  = fmaf(S0, __expf(M0 - ms),
                     fmaf(S1v, __expf(M1 - ms),
                     fmaf(S2, __expf(M2 - ms), S2 * 0.f + S3 * __expf(M3 - ms))));
    const float scale = __expf(mw - ms) / S;   // khi_l = z[l]*scale

    const float kf    = (float)k;
    const float step1 = 0.1f * (lr / sqrtf(kf));
    const float invk  = 1.0f / kf;
    const float om    = 1.0f - invk;
    #pragma unroll
    for (int l = 0; l < EPT; ++l) {
      const float khi = z[l] * scale;
      czh[l]   = fmaf(step1, b[l] - khi, czh[l]);
      avezh[l] = fmaf(invk, czh[l], om * avezh[l]);
    }
  }

  // epilogue: emit w[j] = 0.1*beta + ln b (= avezh + hx), per-sample loss & ot
  float src[EPT], beta[EPT];
  float p_sc = 0.f, p_s1 = 0.f, p_ot = 0.f;
  #pragma unroll
  for (int l = 0; l < EPT; ++l) {
    const int j = l * TPB + t;
    src[l] = unnormed[s * MDIM + j];
    const float hx = 0.1f * (cx[l] * cx[l] + cy[l] * cy[l]);
    const float lb = __logf(b[l]);            // identical to init's value
    const float wj = avezh[l] + hx;
    const float bt = (wj - lb) * 10.0f;
    beta[l] = bt;
    ws[OFF_W + s * MDIM + j] = wj;
    p_sc += src[l];
    p_s1 += src[l] * bt;
    p_ot += b[l] * bt;
  }
  const float sc = blockSum(p_sc, red);
  const float S1 = blockSum(p_s1, red);
  const float ot = blockSum(p_ot, red);
  const float denom = sc * sc + 1e-16f;
  const float c1 = sc / denom, c2 = S1 / denom;
  float pl = 0.f;
  #pragma unroll
  for (int l = 0; l < EPT; ++l)
    pl += src[l] * (c1 * beta[l] - c2);
  const float loss = blockSum(pl, red);
  if (t == 0) {
    ws[OFF_LOSS + s] = loss;
    ws[OFF_OT + s]   = ot;
  }
}

// ---------------- Kernel B: per-row logsumexp + wd partial ------------------
// z_j = w_j - 0.1*M_ij ;  0.1*M_ij recovered as (w_j - z_j)
// wd_row = a_i * 10 * sum(e*(w-z)) / sum(e)
__global__ __launch_bounds__(TPB) void kern_rows(
    const float *__restrict__ pts, float *__restrict__ ws)
{
  const int gid = blockIdx.x;
  const int s = gid >> 9;
  const int i = gid & 511;
  const int t = threadIdx.x;
  __shared__ float red[12];

  const float x = pts[(s * NPTS + i) * 2 + 0];
  const float y = pts[(s * NPTS + i) * 2 + 1];
  const float p2x = 0.2f * x, p2y = 0.2f * y;
  const float sxy = 0.1f * (x * x + y * y);

  float z[EPT], wv[EPT];
  float m0 = -INFINITY, m1 = -INFINITY, m2 = -INFINITY, m3 = -INFINITY;
  #pragma unroll
  for (int l = 0; l < EPT; l += 4) {
    #pragma unroll
    for (int q = 0; q < 4; ++q) {
      const int j = (l + q) * TPB + t;
      const float cxl = (float)((j & 63) * 8 + 4);
      const float cyl = (float)((j >> 6) * 8 + 4);
      const float hx = 0.1f * (cxl * cxl + cyl * cyl);
      const float wj = ws[OFF_W + s * MDIM + j];
      wv[l + q] = wj;
      z[l + q] = fmaf(p2x, cxl, fmaf(p2y, cyl, (wj - hx) - sxy));
    }
    m0 = fmaxf(m0, z[l]);     m1 = fmaxf(m1, z[l + 1]);
    m2 = fmaxf(m2, z[l + 2]); m3 = fmaxf(m3, z[l + 3]);
  }
  float m = waveMax(fmaxf(fmaxf(m0, m1), fmaxf(m2, m3)));
  if ((t & 63) == 0) red[t >> 6] = m;
  __syncthreads();
  m = fmaxf(fmaxf(red[0], red[1]), fmaxf(red[2], red[3]));

  float pe = 0.f, pm = 0.f;
  #pragma unroll
  for (int l = 0; l < EPT; ++l) {
    const float e = __expf(z[l] - m);
    pe += e;
    pm = fmaf(e, wv[l] - z[l], pm);   // e * 0.1*M
  }
  pe = waveSum(pe);
  pm = waveSum(pm);
  if ((t & 63) == 0) { red[4 + (t >> 6)] = pe; red[8 + (t >> 6)] = pm; }
  __syncthreads();
  if (t == 0) {
    const float PE = (red[4] + red[5]) + (red[6] + red[7]);
    const float PM = (red[8] + red[9]) + (red[10] + red[11]);
    ws[OFF_WD + gid] = (10.0f / 512.0f) * (PM / PE);
  }
}

// ---------------- Kernel C: deterministic final reduce ----------------------
__global__ __launch_bounds__(TPB) void kern_final(const float *__restrict__ ws,
                                                  float *__restrict__ out)
{
  const int t = threadIdx.x;
  __shared__ float red[4];
  float v = 0.f;
  for (int i = t; i < NSAMP * NPTS; i += TPB) v += ws[OFF_WD + i];
  const float wd = blockSum(v, red);
  if (t == 0) {
    float ls = 0.f, ot = 0.f;
    for (int s2 = 0; s2 < NSAMP; ++s2) { ls += ws[OFF_LOSS + s2]; ot += ws[OFF_OT + s2]; }
    out[0] = ls;   // loss.sum()
    out[1] = wd;   // wd.sum()
    out[2] = ot;   // ot_obj.sum()
  }
}

extern "C" void kernel_launch(void* const* d_in, const int* in_sizes, int n_in,
                              void* d_out, int out_size, void* d_ws, size_t ws_size,
                              hipStream_t stream)
{
  (void)in_sizes; (void)n_in; (void)out_size; (void)ws_size;
  const float *normed   = (const float *)d_in[0];
  const float *unnormed = (const float *)d_in[1];
  const float *pts      = (const float *)d_in[2];
  float *out = (float *)d_out;
  float *ws  = (float *)d_ws;

  kern_scan <<<dim3(NSAMP),        dim3(TPB), 0, stream>>>(normed, unnormed, pts, ws);
  kern_rows <<<dim3(NSAMP * NPTS), dim3(TPB), 0, stream>>>(pts, ws);
  kern_final<<<dim3(1),            dim3(TPB), 0, stream>>>(ws, out);
}

// Round 3
// 154.726 us; speedup vs baseline: 2.3647x; 1.0655x over previous
//
#include <hip/hip_runtime.h>
#include <math.h>

// Problem constants (from reference)
#define NSAMP 16
#define NPTS  512
#define MDIM  4096     // 64*64 grid
#define NIT   100

// scan: 1024 threads = 16 waves; wave w owns grid rows [4w,4w+4), lane = column
#define STPB  1024
#define SEPT  4
// rows: 256 threads = 4 waves; wave w owns grid rows [16w,16w+16); 4 point-rows per block
#define RTPB  256
#define REPT  16
#define RPB   4

// ws layout (floats)
#define OFF_W    0                          // 16*4096: w[j] = 0.1*beta_j + ln(b_j)
#define OFF_WD   (NSAMP * MDIM)             // 8192 per-row wd partials
#define OFF_LOSS (OFF_WD + NSAMP * NPTS)    // 16 per-sample loss
#define OFF_OT   (OFF_LOSS + NSAMP)         // 16 per-sample ot_obj

// ---------------- Threefry-2x32 (JAX-exact, partitionable path; R0-verified)
__device__ __forceinline__ void tf2x32(unsigned k0, unsigned k1,
                                       unsigned c0, unsigned c1,
                                       unsigned &o0, unsigned &o1)
{
  unsigned ks2 = k0 ^ k1 ^ 0x1BD11BDAu;
  unsigned x0 = c0 + k0, x1 = c1 + k1;
#define ROT(r) x0 += x1; x1 = (x1 << (r)) | (x1 >> (32 - (r))); x1 ^= x0;
#define G0 ROT(13) ROT(15) ROT(26) ROT(6)
#define G1 ROT(17) ROT(29) ROT(16) ROT(24)
  G0 x0 += k1;  x1 += ks2 + 1u;
  G1 x0 += ks2; x1 += k0  + 2u;
  G0 x0 += k0;  x1 += k1  + 3u;
  G1 x0 += k1;  x1 += ks2 + 4u;
  G0 x0 += ks2; x1 += k0  + 5u;
#undef G0
#undef G1
#undef ROT
  o0 = x0; o1 = x1;
}

__device__ __forceinline__ int rand_idx(int f)
{
  unsigned ka, kb, w0, w1;
  tf2x32(0u, 1u, 0u, 1u, ka, kb);            // split(key(1))[1]
  tf2x32(ka, kb, 0u, (unsigned)f, w0, w1);   // random_bits elem f
  return (int)((w0 ^ w1) & 511u);
}

// ---------------- wave64 reductions via DPP (R1-verified) -------------------
template<int CTRL>
__device__ __forceinline__ float dpp_mv(float v, float id)
{
  return __int_as_float(__builtin_amdgcn_update_dpp(
      __float_as_int(id), __float_as_int(v), CTRL, 0xF, 0xF, false));
}

__device__ __forceinline__ float waveMax(float v)
{
  v = fmaxf(v, dpp_mv<0x111>(v, -INFINITY));
  v = fmaxf(v, dpp_mv<0x112>(v, -INFINITY));
  v = fmaxf(v, dpp_mv<0x114>(v, -INFINITY));
  v = fmaxf(v, dpp_mv<0x118>(v, -INFINITY));
  v = fmaxf(v, dpp_mv<0x142>(v, -INFINITY));
  v = fmaxf(v, dpp_mv<0x143>(v, -INFINITY));
  return __int_as_float(__builtin_amdgcn_readlane(__float_as_int(v), 63));
}

__device__ __forceinline__ float waveSum(float v)
{
  v += dpp_mv<0x111>(v, 0.0f);
  v += dpp_mv<0x112>(v, 0.0f);
  v += dpp_mv<0x114>(v, 0.0f);
  v += dpp_mv<0x118>(v, 0.0f);
  v += dpp_mv<0x142>(v, 0.0f);
  v += dpp_mv<0x143>(v, 0.0f);
  return __int_as_float(__builtin_amdgcn_readlane(__float_as_int(v), 63));
}

// ---------------- Kernel A: per-sample ASGD scan ----------------------------
// 16 waves (4/SIMD). Wave w owns rows [4w,4w+4), lane L = column.
// State: czh = 0.1*cur + ln b - hx, hx = 0.1*(cx^2+cy^2); z = 0.1*(cur-M)+ln b.
// Two barriers/iter: (1) exchange per-wave true max -> gm; (2) exchange S_w.
// Wave skip (EXACT): if mw < gm-88, every exp underflows to 0 in fp32, khi=0.
__global__ __launch_bounds__(STPB) void kern_scan(
    const float *__restrict__ normed, const float *__restrict__ unnormed,
    const float *__restrict__ pts, float *__restrict__ ws)
{
  const int s = blockIdx.x;
  const int t = threadIdx.x;
  const int w = t >> 6;        // 0..15
  const int L = t & 63;
  __shared__ float px[NPTS], py[NPTS];
  __shared__ int   sidx[NIT];
  __shared__ float mlds[16];
  __shared__ float slds[16];
  __shared__ float r0[16], r1[16], r2[16];

  if (t < NPTS) {
    px[t] = pts[(s * NPTS + t) * 2 + 0];
    py[t] = pts[(s * NPTS + t) * 2 + 1];
  }
  if (t < NIT) sidx[t] = rand_idx(s * NIT + t);

  const float cxL = (float)(L * 8 + 4);
  float b[SEPT], czh[SEPT], avezh[SEPT], cyv[SEPT];
  #pragma unroll
  for (int l = 0; l < SEPT; ++l) {
    const int j = w * 256 + l * 64 + L;          // row = 4w+l, col = L
    const float bv = normed[s * MDIM + j];
    b[l] = bv;
    const float cy = (float)((4 * w + l) * 8 + 4);
    cyv[l] = cy;
    const float hx = 0.1f * (cxL * cxL + cy * cy);
    czh[l]   = __logf(bv) - hx;
    avezh[l] = 0.f;
  }
  __syncthreads();

  for (int k = 1; k <= NIT; ++k) {
    const int   i = sidx[k - 1];
    const float x = px[i], y = py[i];
    const float p2x = 0.2f * x, p2y = 0.2f * y;
    const float sxy = 0.1f * (x * x + y * y);
    const float base = fmaf(p2x, cxL, -sxy);

    float z[SEPT];
    #pragma unroll
    for (int l = 0; l < SEPT; ++l)
      z[l] = fmaf(p2y, cyv[l], czh[l] + base);

    const float mx = fmaxf(fmaxf(z[0], z[1]), fmaxf(z[2], z[3]));
    const float mw = waveMax(mx);
    if (L == 0) mlds[w] = mw;
    __syncthreads();                                   // barrier 1
    const float gm = waveMax(mlds[L & 15]);

    const float kf    = (float)k;
    const float step1 = 512.0f * __builtin_amdgcn_rsqf(kf);  // 0.1*lr/sqrt(k)
    const float invk  = __builtin_amdgcn_rcpf(kf);
    const float om    = 1.0f - invk;

    const bool active = (mw >= gm - 88.0f);
    float e[SEPT];
    if (active) {
      #pragma unroll
      for (int l = 0; l < SEPT; ++l)
        e[l] = __expf(z[l] - gm);
      const float sw = waveSum((e[0] + e[1]) + (e[2] + e[3]));
      if (L == 0) slds[w] = sw;
    } else {
      if (L == 0) slds[w] = 0.0f;
      // khi == 0 exactly; finish update before barrier 2 (off critical path)
      #pragma unroll
      for (int l = 0; l < SEPT; ++l) {
        czh[l]   = fmaf(step1, b[l], czh[l]);
        avezh[l] = fmaf(invk, czh[l], om * avezh[l]);
      }
    }
    __syncthreads();                                   // barrier 2
    if (active) {
      float v = slds[L & 15];
      v = (L < 16) ? v : 0.0f;
      const float S    = waveSum(v);
      const float invS = 1.0f / S;
      #pragma unroll
      for (int l = 0; l < SEPT; ++l) {
        czh[l]   = fmaf(step1, b[l] - e[l] * invS, czh[l]);
        avezh[l] = fmaf(invk, czh[l], om * avezh[l]);
      }
    }
  }

  // epilogue: w[j] = avezh + hx; per-sample loss & ot
  float src[SEPT], beta[SEPT];
  float p_sc = 0.f, p_s1 = 0.f, p_ot = 0.f;
  #pragma unroll
  for (int l = 0; l < SEPT; ++l) {
    const int j = w * 256 + l * 64 + L;
    const float sv = unnormed[s * MDIM + j];
    src[l] = sv;
    const float hx = 0.1f * (cxL * cxL + cyv[l] * cyv[l]);
    const float wj = avezh[l] + hx;
    const float bt = (wj - __logf(b[l])) * 10.0f;
    ws[OFF_W + s * MDIM + j] = wj;
    beta[l] = bt;
    p_sc += sv;
    p_s1 += sv * bt;
    p_ot += b[l] * bt;
  }
  p_sc = waveSum(p_sc); p_s1 = waveSum(p_s1); p_ot = waveSum(p_ot);
  if (L == 0) { r0[w] = p_sc; r1[w] = p_s1; r2[w] = p_ot; }
  __syncthreads();
  float sc = 0.f, S1 = 0.f, ot = 0.f;
  #pragma unroll
  for (int i2 = 0; i2 < 16; ++i2) { sc += r0[i2]; S1 += r1[i2]; ot += r2[i2]; }
  const float denom = sc * sc + 1e-16f;
  const float c1 = sc / denom, c2 = S1 / denom;
  float pl = 0.f;
  #pragma unroll
  for (int l = 0; l < SEPT; ++l)
    pl += src[l] * (c1 * beta[l] - c2);
  pl = waveSum(pl);
  __syncthreads();                  // WAR on r0 reuse
  if (L == 0) r0[w] = pl;
  __syncthreads();
  if (t == 0) {
    float loss = 0.f;
    #pragma unroll
    for (int i2 = 0; i2 < 16; ++i2) loss += r0[i2];
    ws[OFF_LOSS + s] = loss;
    ws[OFF_OT + s]   = ot;
  }
}

// ---------------- Kernel B: per-row logsumexp + wd partial ------------------
// Block handles 4 point-rows of one sample; w_j loads amortized over them.
// Wave w owns grid rows [16w,16w+16), lane = column -> exact wave skip.
// q = M = dx^2+dy^2; z = w_j - 0.1*q; wd_row = (1/512) * sum(e*q)/sum(e).
__global__ __launch_bounds__(RTPB) void kern_rows(
    const float *__restrict__ pts, float *__restrict__ ws)
{
  const int bid = blockIdx.x;
  const int s = bid >> 7;
  const int g = bid & 127;          // point-rows 4g..4g+3
  const int t = threadIdx.x;
  const int w = t >> 6;
  const int L = t & 63;
  __shared__ float mred[4], ered[4], qred[4];

  const float cxL = (float)(L * 8 + 4);
  const float cyw = (float)(w * 128 + 4);   // cy of slab row 0

  float wv[REPT];
  #pragma unroll
  for (int l = 0; l < REPT; ++l) {
    const int j = (16 * w + l) * 64 + L;
    wv[l] = ws[OFF_W + s * MDIM + j];
  }

  for (int r = 0; r < RPB; ++r) {
    const int row = 4 * g + r;
    const float x = pts[(s * NPTS + row) * 2 + 0];
    const float y = pts[(s * NPTS + row) * 2 + 1];
    const float dx = x - cxL;
    const float dxx = dx * dx;
    const float ty = y - cyw;                 // dy_l = ty - 8l

    float q[REPT];
    float m0 = -INFINITY, m1 = -INFINITY, m2 = -INFINITY, m3 = -INFINITY;
    #pragma unroll
    for (int l = 0; l < REPT; l += 4) {
      #pragma unroll
      for (int u = 0; u < 4; ++u) {
        const float dy = ty - (float)(8 * (l + u));
        q[l + u] = fmaf(dy, dy, dxx);
      }
      m0 = fmaxf(m0, fmaf(-0.1f, q[l],     wv[l]));
      m1 = fmaxf(m1, fmaf(-0.1f, q[l + 1], wv[l + 1]));
      m2 = fmaxf(m2, fmaf(-0.1f, q[l + 2], wv[l + 2]));
      m3 = fmaxf(m3, fmaf(-0.1f, q[l + 3], wv[l + 3]));
    }
    const float mw = waveMax(fmaxf(fmaxf(m0, m1), fmaxf(m2, m3)));
    if (L == 0) mred[w] = mw;
    __syncthreads();
    const float gm = fmaxf(fmaxf(mred[0], mred[1]), fmaxf(mred[2], mred[3]));

    float pe = 0.f, pq = 0.f;
    if (mw >= gm - 88.0f) {                   // exact skip (exp underflow)
      #pragma unroll
      for (int l = 0; l < REPT; ++l) {
        const float zz = fmaf(-0.1f, q[l], wv[l]);
        const float e = __expf(zz - gm);
        pe += e;
        pq = fmaf(e, q[l], pq);
      }
      pe = waveSum(pe);
      pq = waveSum(pq);
    }
    if (L == 0) { ered[w] = pe; qred[w] = pq; }
    __syncthreads();
    if (t == 0) {
      const float PE = (ered[0] + ered[1]) + (ered[2] + ered[3]);
      const float PQ = (qred[0] + qred[1]) + (qred[2] + qred[3]);
      ws[OFF_WD + s * NPTS + row] = (1.0f / 512.0f) * (PQ / PE);
    }
  }
}

// ---------------- Kernel C: deterministic final reduce ----------------------
__global__ __launch_bounds__(RTPB) void kern_final(const float *__restrict__ ws,
                                                   float *__restrict__ out)
{
  const int t = threadIdx.x;
  __shared__ float red[4];
  const float4 *p4 = (const float4 *)(ws + OFF_WD);
  float v = 0.f;
  for (int i = t; i < (NSAMP * NPTS) / 4; i += RTPB) {
    const float4 f = p4[i];
    v += (f.x + f.y) + (f.z + f.w);
  }
  v = waveSum(v);
  if ((t & 63) == 0) red[t >> 6] = v;
  __syncthreads();
  if (t == 0) {
    const float wd = (red[0] + red[1]) + (red[2] + red[3]);
    float ls = 0.f, ot = 0.f;
    for (int s2 = 0; s2 < NSAMP; ++s2) { ls += ws[OFF_LOSS + s2]; ot += ws[OFF_OT + s2]; }
    out[0] = ls;   // loss.sum()
    out[1] = wd;   // wd.sum()
    out[2] = ot;   // ot_obj.sum()
  }
}

extern "C" void kernel_launch(void* const* d_in, const int* in_sizes, int n_in,
                              void* d_out, int out_size, void* d_ws, size_t ws_size,
                              hipStream_t stream)
{
  (void)in_sizes; (void)n_in; (void)out_size; (void)ws_size;
  const float *normed   = (const float *)d_in[0];
  const float *unnormed = (const float *)d_in[1];
  const float *pts      = (const float *)d_in[2];
  float *out = (float *)d_out;
  float *ws  = (float *)d_ws;

  kern_scan <<<dim3(NSAMP),       dim3(STPB), 0, stream>>>(normed, unnormed, pts, ws);
  kern_rows <<<dim3(NSAMP * 128), dim3(RTPB), 0, stream>>>(pts, ws);
  kern_final<<<dim3(1),           dim3(RTPB), 0, stream>>>(ws, out);
}